// Round 3
// baseline (505.753 us; speedup 1.0000x reference)
//
#include <hip/hip_runtime.h>
#include <hip/hip_bf16.h>
#include <stdint.h>
#include <stddef.h>

typedef __bf16 bf16;
typedef bf16 bf16x8 __attribute__((ext_vector_type(8)));
typedef float f32x4 __attribute__((ext_vector_type(4)));

#define N_ROWS 65536
#define EMB    1024
#define ATTD   512
#define KDIM   2048
#define BM     128
#define BK     64
#define NKB    (KDIM / BK)     // 32 K-tiles
#define NBLK   (N_ROWS / BM)   // 512

__device__ __forceinline__ void gload_lds16(const void* g, void* l) {
  __builtin_amdgcn_global_load_lds(
      (const __attribute__((address_space(1))) void*)g,
      (__attribute__((address_space(3))) void*)l, 16, 0, 0);
}

// ---------------------------------------------------------------------------
// K0: W1 [2048x512] f32 -> W1t bf16: 32 per-K-tile 64 KiB images.
// Image kb, linear elem addr (n*8 + p)*8 + e  holds  W1[kb*64 + (p^(n&7))*8 + e][n].
// (XOR chunk swizzle pre-applied in global so K1's linear global_load_lds
//  deposits the swizzled layout; K1 reads with the same XOR — rule #21.)
// ---------------------------------------------------------------------------
__global__ __launch_bounds__(256) void k_prep_w1(const float* __restrict__ W1,
                                                 bf16* __restrict__ W1t) {
  __shared__ float tile[64][72];
  const int kb = blockIdx.x;   // 0..31
  const int ng = blockIdx.y;   // 0..7
  const int t  = threadIdx.x;  // 0..255
  const int n0 = ng * 64;

  const int kr = t >> 2;            // 0..63
  const int nc = (t & 3) * 16;
  const float* src = W1 + (size_t)(kb * 64 + kr) * ATTD + n0 + nc;
  #pragma unroll
  for (int q = 0; q < 4; ++q) {
    float4 v = *(const float4*)(src + q * 4);
    tile[kr][nc + q * 4 + 0] = v.x;
    tile[kr][nc + q * 4 + 1] = v.y;
    tile[kr][nc + q * 4 + 2] = v.z;
    tile[kr][nc + q * 4 + 3] = v.w;
  }
  __syncthreads();

  const int nl = t >> 2;            // 0..63
  const int n  = n0 + nl;
  #pragma unroll
  for (int h = 0; h < 2; ++h) {
    const int p = (t & 3) + h * 4;  // physical chunk 0..7
    const int c = p ^ (n & 7);      // logical chunk
    bf16x8 o;
    #pragma unroll
    for (int e = 0; e < 8; ++e) o[e] = (bf16)tile[c * 8 + e][nl];
    *(bf16x8*)(W1t + (size_t)kb * (ATTD * BK) + ((size_t)n * 8 + p) * 8) = o;
  }
}

// ---------------------------------------------------------------------------
// K1: fused GEMM (M=65536,N=512,K=2048 bf16) + tanh-MLP score + block softmax
// stats. 512 blocks x 512 thr (8 waves, 2Mx4N). BK=64. Deep pipeline with
// counted vmcnt across raw s_barrier (T3+T4): B(kb+1) DMA + A(kb+2)->regs in
// flight during compute of kb; never drain vmcnt to 0 in the main loop.
// ---------------------------------------------------------------------------
__global__ __launch_bounds__(512, 2) void k_gemm_score(
    const float* __restrict__ leaves, const float* __restrict__ anc,
    const bf16* __restrict__ W1t, const float* __restrict__ b1,
    const float* __restrict__ W2, const float* __restrict__ b2,
    float* __restrict__ scores, float* __restrict__ bmax,
    float* __restrict__ bsum) {
  __shared__ bf16 ldsA[2][BM * BK];    // 2 x 16 KiB
  __shared__ bf16 ldsB[2][ATTD * BK];  // 2 x 64 KiB   (total 160 KiB)

  const int t    = threadIdx.x;
  const int lane = t & 63;
  const int wave = t >> 6;
  const int l15  = lane & 15;
  const int l4   = lane >> 4;
  const int wm   = wave >> 2;  // 0..1
  const int wn   = wave & 3;   // 0..3
  const int m0   = blockIdx.x * BM;

  // A staging: 4 threads/row, each 16 f32 (2 logical chunks of 8)
  const int ar  = t >> 2;        // 0..127
  const int acb = (t & 3) * 2;   // logical chunk base (0,2,4,6)

  const f32x4 zero4 = {0.f, 0.f, 0.f, 0.f};
  f32x4 acc[4][8];
  #pragma unroll
  for (int i = 0; i < 4; ++i)
    #pragma unroll
    for (int j = 0; j < 8; ++j) acc[i][j] = zero4;

  float4 rA0[4], rA1[4];

  // ---- prologue: A(0)->rA0, B(0)->ldsB[0] DMA, A(1)->rA1; write A(0) ----
  {
    const float* Ap0 = leaves + (size_t)(m0 + ar) * EMB + acb * 8;
    rA0[0] = *(const float4*)(Ap0 + 0);
    rA0[1] = *(const float4*)(Ap0 + 4);
    rA0[2] = *(const float4*)(Ap0 + 8);
    rA0[3] = *(const float4*)(Ap0 + 12);
    #pragma unroll
    for (int j = 0; j < 8; ++j)
      gload_lds16(W1t + ((size_t)(wave * 8 + j) * 64 + lane) * 8,
                  &ldsB[0][(wave * 8 + j) * 512]);
    const float* Ap1 = leaves + (size_t)(m0 + ar) * EMB + BK + acb * 8;
    rA1[0] = *(const float4*)(Ap1 + 0);
    rA1[1] = *(const float4*)(Ap1 + 4);
    rA1[2] = *(const float4*)(Ap1 + 8);
    rA1[3] = *(const float4*)(Ap1 + 12);
    __builtin_amdgcn_sched_barrier(0);
    bf16x8 o0 = {(bf16)rA0[0].x, (bf16)rA0[0].y, (bf16)rA0[0].z, (bf16)rA0[0].w,
                 (bf16)rA0[1].x, (bf16)rA0[1].y, (bf16)rA0[1].z, (bf16)rA0[1].w};
    bf16x8 o1 = {(bf16)rA0[2].x, (bf16)rA0[2].y, (bf16)rA0[2].z, (bf16)rA0[2].w,
                 (bf16)rA0[3].x, (bf16)rA0[3].y, (bf16)rA0[3].z, (bf16)rA0[3].w};
    *(bf16x8*)(&ldsA[0][ar * BK + ((acb + 0) ^ (ar & 7)) * 8]) = o0;
    *(bf16x8*)(&ldsA[0][ar * BK + ((acb + 1) ^ (ar & 7)) * 8]) = o1;
    asm volatile("s_waitcnt vmcnt(4) lgkmcnt(0)" ::: "memory");
    __builtin_amdgcn_s_barrier();
  }

#define GEMM_BODY(KB, CUR, RISS, RWR, DOSTAGE, DOAISS)                         \
  do {                                                                         \
    if (DOSTAGE) {                                                             \
      const bf16* Bsrc_ = W1t + (size_t)((KB) + 1) * (ATTD * BK);              \
      _Pragma("unroll")                                                        \
      for (int j = 0; j < 8; ++j)                                              \
        gload_lds16(Bsrc_ + ((size_t)(wave * 8 + j) * 64 + lane) * 8,          \
                    &ldsB[(CUR) ^ 1][(wave * 8 + j) * 512]);                   \
      if (DOAISS) {                                                            \
        const int kn_ = (KB) + 2;                                              \
        const float* Ap_ = (kn_ < 16)                                          \
            ? leaves + (size_t)(m0 + ar) * EMB + (size_t)kn_ * BK + acb * 8    \
            : anc + (size_t)(m0 + ar) * EMB + (size_t)(kn_ - 16) * BK + acb * 8;\
        RISS[0] = *(const float4*)(Ap_ + 0);                                   \
        RISS[1] = *(const float4*)(Ap_ + 4);                                   \
        RISS[2] = *(const float4*)(Ap_ + 8);                                   \
        RISS[3] = *(const float4*)(Ap_ + 12);                                  \
      }                                                                        \
      __builtin_amdgcn_sched_barrier(0);                                       \
    }                                                                          \
    _Pragma("unroll")                                                          \
    for (int ks = 0; ks < 2; ++ks) {                                           \
      bf16x8 af_[4], bf_[8];                                                   \
      _Pragma("unroll")                                                        \
      for (int mi = 0; mi < 4; ++mi) {                                         \
        const int row_ = wm * 64 + mi * 16 + l15;                              \
        const int p_   = (ks * 4 + l4) ^ (row_ & 7);                           \
        af_[mi] = *(const bf16x8*)(&ldsA[CUR][row_ * BK + p_ * 8]);            \
      }                                                                        \
      _Pragma("unroll")                                                        \
      for (int ni = 0; ni < 8; ++ni) {                                         \
        const int nrow_ = wn * 128 + ni * 16 + l15;                            \
        const int p_    = (ks * 4 + l4) ^ (nrow_ & 7);                         \
        bf_[ni] = *(const bf16x8*)(&ldsB[CUR][nrow_ * BK + p_ * 8]);           \
      }                                                                        \
      _Pragma("unroll")                                                        \
      for (int ni = 0; ni < 8; ++ni)                                           \
        _Pragma("unroll")                                                      \
        for (int mi = 0; mi < 4; ++mi)                                         \
          acc[mi][ni] = __builtin_amdgcn_mfma_f32_16x16x32_bf16(               \
              af_[mi], bf_[ni], acc[mi][ni], 0, 0, 0);                         \
    }                                                                          \
    if (DOSTAGE) {                                                             \
      bf16x8 w0_ = {(bf16)RWR[0].x, (bf16)RWR[0].y, (bf16)RWR[0].z,            \
                    (bf16)RWR[0].w, (bf16)RWR[1].x, (bf16)RWR[1].y,            \
                    (bf16)RWR[1].z, (bf16)RWR[1].w};                           \
      bf16x8 w1_ = {(bf16)RWR[2].x, (bf16)RWR[2].y, (bf16)RWR[2].z,            \
                    (bf16)RWR[2].w, (bf16)RWR[3].x, (bf16)RWR[3].y,            \
                    (bf16)RWR[3].z, (bf16)RWR[3].w};                           \
      *(bf16x8*)(&ldsA[(CUR) ^ 1][ar * BK + ((acb + 0) ^ (ar & 7)) * 8]) = w0_;\
      *(bf16x8*)(&ldsA[(CUR) ^ 1][ar * BK + ((acb + 1) ^ (ar & 7)) * 8]) = w1_;\
      if (DOAISS) {                                                            \
        asm volatile("s_waitcnt vmcnt(4) lgkmcnt(0)" ::: "memory");            \
      } else {                                                                 \
        asm volatile("s_waitcnt vmcnt(0) lgkmcnt(0)" ::: "memory");            \
      }                                                                        \
    } else {                                                                   \
      asm volatile("s_waitcnt lgkmcnt(0)" ::: "memory");                       \
    }                                                                          \
    __builtin_amdgcn_s_barrier();                                              \
  } while (0)

  for (int kbp = 0; kbp < 15; ++kbp) {
    const int kb = kbp * 2;
    GEMM_BODY(kb,     0, rA0, rA1, true, true);
    GEMM_BODY(kb + 1, 1, rA1, rA0, true, true);
  }
  GEMM_BODY(30, 0, rA0, rA1, true,  false);  // stage B(31), write A(31) from rA1
  GEMM_BODY(31, 1, rA0, rA1, false, false);  // compute only
#undef GEMM_BODY

  // ---- epilogue: score[r] = b2 + sum_col tanh(h + b1[col]) * W2[col] ----
  // acc[mi][ni][reg]: row = wm*64+mi*16+l4*4+reg, col = wn*128+ni*16+l15
  float b1c[8], w2c[8];
  #pragma unroll
  for (int ni = 0; ni < 8; ++ni) {
    const int col = wn * 128 + ni * 16 + l15;
    b1c[ni] = b1[col];
    w2c[ni] = W2[col];
  }
  float* sp   = (float*)&ldsA[0][0];
  float* redm = sp + 512;
  float* redz = sp + 520;
  #pragma unroll
  for (int mi = 0; mi < 4; ++mi) {
    #pragma unroll
    for (int r = 0; r < 4; ++r) {
      float p = 0.f;
      #pragma unroll
      for (int ni = 0; ni < 8; ++ni)
        p += tanhf(acc[mi][ni][r] + b1c[ni]) * w2c[ni];
      p += __shfl_xor(p, 1);
      p += __shfl_xor(p, 2);
      p += __shfl_xor(p, 4);
      p += __shfl_xor(p, 8);
      if (l15 == 0) sp[wn * 128 + wm * 64 + mi * 16 + l4 * 4 + r] = p;
    }
  }
  __syncthreads();
  float myscore = 0.f;
  if (t < BM) {
    myscore = sp[t] + sp[128 + t] + sp[256 + t] + sp[384 + t] + b2[0];
    scores[m0 + t] = myscore;
  }
  float mm = (t < BM) ? myscore : -3.0e38f;
  #pragma unroll
  for (int o = 32; o; o >>= 1) mm = fmaxf(mm, __shfl_xor(mm, o));
  if (lane == 0) redm[wave] = mm;
  __syncthreads();
  if (t == 0) {
    float g = redm[0];
    for (int i = 1; i < 8; ++i) g = fmaxf(g, redm[i]);
    redm[0] = g;
  }
  __syncthreads();
  const float bM = redm[0];
  float ee = (t < BM) ? __expf(myscore - bM) : 0.f;
  #pragma unroll
  for (int o = 32; o; o >>= 1) ee += __shfl_xor(ee, o);
  if (lane == 0) redz[wave] = ee;
  __syncthreads();
  if (t == 0) {
    float z = 0.f;
    for (int i = 0; i < 8; ++i) z += redz[i];
    bmax[blockIdx.x] = bM;
    bsum[blockIdx.x] = z;
  }
}

// ---------------------------------------------------------------------------
// K2: reduce 512 per-block (max, sumexp) pairs -> global M, Z
// ---------------------------------------------------------------------------
__global__ __launch_bounds__(512) void k_mz(const float* __restrict__ bmax,
                                            const float* __restrict__ bsum,
                                            float* __restrict__ MZ) {
  const int t = threadIdx.x, lane = t & 63, wave = t >> 6;
  __shared__ float rm[8], rs[8];
  const float m = bmax[t];
  float mm = m;
  #pragma unroll
  for (int o = 32; o; o >>= 1) mm = fmaxf(mm, __shfl_xor(mm, o));
  if (lane == 0) rm[wave] = mm;
  __syncthreads();
  if (t == 0) {
    float g = rm[0];
    for (int i = 1; i < 8; ++i) g = fmaxf(g, rm[i]);
    rm[0] = g;
  }
  __syncthreads();
  const float M = rm[0];
  float z = bsum[t] * __expf(m - M);
  #pragma unroll
  for (int o = 32; o; o >>= 1) z += __shfl_xor(z, o);
  if (lane == 0) rs[wave] = z;
  __syncthreads();
  if (t == 0) {
    float Z = 0.f;
    for (int i = 0; i < 8; ++i) Z += rs[i];
    MZ[0] = M;
    MZ[1] = Z;
  }
}

// ---------------------------------------------------------------------------
// K3: per-block partial weighted sum: part[b][j] = sum_i exp(s_i - M)*anc[i][j]
// ---------------------------------------------------------------------------
__global__ __launch_bounds__(256) void k_part(const float* __restrict__ anc,
                                              const float* __restrict__ scores,
                                              const float* __restrict__ MZ,
                                              float* __restrict__ part) {
  __shared__ float w[BM];
  const int b = blockIdx.x, t = threadIdx.x;
  const float M = MZ[0];
  if (t < BM) w[t] = __expf(scores[(size_t)b * BM + t] - M);
  __syncthreads();
  float4 a = {0.f, 0.f, 0.f, 0.f};
  const float4* src = (const float4*)(anc + (size_t)b * BM * EMB) + t;
  #pragma unroll 4
  for (int i = 0; i < BM; ++i) {
    float4 v = src[i * (EMB / 4)];
    const float wi = w[i];
    a.x += wi * v.x;
    a.y += wi * v.y;
    a.z += wi * v.z;
    a.w += wi * v.w;
  }
  ((float4*)(part + (size_t)b * EMB))[t] = a;
}

// ---------------------------------------------------------------------------
// K4: out[j] = (sum_b part[b][j]) / Z
// ---------------------------------------------------------------------------
__global__ __launch_bounds__(256) void k_final(const float* __restrict__ part,
                                               const float* __restrict__ MZ,
                                               float* __restrict__ out) {
  const int j = blockIdx.x * 256 + threadIdx.x;
  float s0 = 0.f, s1 = 0.f, s2 = 0.f, s3 = 0.f;
  for (int b = 0; b < NBLK; b += 4) {
    s0 += part[(size_t)(b + 0) * EMB + j];
    s1 += part[(size_t)(b + 1) * EMB + j];
    s2 += part[(size_t)(b + 2) * EMB + j];
    s3 += part[(size_t)(b + 3) * EMB + j];
  }
  out[j] = (s0 + s1 + s2 + s3) / MZ[1];
}

extern "C" void kernel_launch(void* const* d_in, const int* in_sizes, int n_in,
                              void* d_out, int out_size, void* d_ws,
                              size_t ws_size, hipStream_t stream) {
  const float* leaves = (const float*)d_in[0];
  const float* anc    = (const float*)d_in[1];
  const float* W1     = (const float*)d_in[2];
  const float* b1     = (const float*)d_in[3];
  const float* W2     = (const float*)d_in[4];
  const float* b2     = (const float*)d_in[5];
  float* out = (float*)d_out;

  char* ws = (char*)d_ws;
  bf16*  W1t    = (bf16*)ws;                                  // 2 MiB
  float* scores = (float*)(ws + (1u << 21));                  // 256 KiB
  float* bmax   = (float*)(ws + (1u << 21) + (1u << 18));     // 2 KiB
  float* bsum   = bmax + NBLK;                                // 2 KiB
  float* MZ     = bsum + NBLK;                                // 8 B
  float* part   = (float*)(ws + (1u << 21) + (1u << 19));     // 2 MiB

  k_prep_w1<<<dim3(32, 8), 256, 0, stream>>>(W1, W1t);
  k_gemm_score<<<dim3(NBLK), 512, 0, stream>>>(leaves, anc, W1t, b1, W2, b2,
                                               scores, bmax, bsum);
  k_mz<<<dim3(1), 512, 0, stream>>>(bmax, bsum, MZ);
  k_part<<<dim3(NBLK), 256, 0, stream>>>(anc, scores, MZ, part);
  k_final<<<dim3(EMB / 256), 256, 0, stream>>>(part, MZ, out);
}

// Round 4
// 410.277 us; speedup vs baseline: 1.2327x; 1.2327x over previous
//
#include <hip/hip_runtime.h>
#include <hip/hip_bf16.h>
#include <stdint.h>
#include <stddef.h>

typedef __bf16 bf16;
typedef bf16 bf16x8 __attribute__((ext_vector_type(8)));
typedef float f32x4 __attribute__((ext_vector_type(4)));

#define N_ROWS 65536
#define EMB    1024
#define ATTD   512
#define KDIM   2048
#define BM     128
#define BN     128
#define BK     64
#define NKB    (KDIM / BK)     // 32 K-tiles
#define MBLK   (N_ROWS / BM)   // 512 row-blocks
#define NSPL   (ATTD / BN)     // 4 col-blocks

__device__ __forceinline__ void gload_lds16(const void* g, void* l) {
  __builtin_amdgcn_global_load_lds(
      (const __attribute__((address_space(1))) void*)g,
      (__attribute__((address_space(3))) void*)l, 16, 0, 0);
}

// ---------------------------------------------------------------------------
// K0: W1 [2048x512] f32 -> W1t bf16: 32x4 per-(kb,bn) 16 KiB images.
// Image (kb,bn), elem (n*8+p)*8+e  holds  W1[kb*64 + (p^(n&7))*8 + e][bn*128+n].
// XOR chunk swizzle pre-applied in global memory so K1's linear global_load_lds
// deposits the swizzled layout; K1 reads with the same XOR (rule #21).
// ---------------------------------------------------------------------------
__global__ __launch_bounds__(256) void k_prep_w1(const float* __restrict__ W1,
                                                 bf16* __restrict__ W1t) {
  __shared__ float tile[64][132];
  const int kb = blockIdx.x;   // 0..31
  const int bn = blockIdx.y;   // 0..3
  const int t  = threadIdx.x;  // 0..255

  const int kr = t >> 2;             // 0..63
  const int nc = (t & 3) * 32;       // 0,32,64,96
  const float* src = W1 + (size_t)(kb * 64 + kr) * ATTD + bn * 128 + nc;
  #pragma unroll
  for (int q = 0; q < 8; ++q) {
    float4 v = *(const float4*)(src + q * 4);
    tile[kr][nc + q * 4 + 0] = v.x;
    tile[kr][nc + q * 4 + 1] = v.y;
    tile[kr][nc + q * 4 + 2] = v.z;
    tile[kr][nc + q * 4 + 3] = v.w;
  }
  __syncthreads();

  const int nl = t >> 1;             // 0..127
  const int pb = (t & 1) * 4;
  bf16* dst = W1t + (size_t)(kb * 4 + bn) * (BN * BK);
  #pragma unroll
  for (int pi = 0; pi < 4; ++pi) {
    const int p = pb + pi;
    const int c = p ^ (nl & 7);
    bf16x8 o;
    #pragma unroll
    for (int e = 0; e < 8; ++e) o[e] = (bf16)tile[c * 8 + e][nl];
    *(bf16x8*)(dst + ((size_t)nl * 8 + p) * 8) = o;
  }
}

// ---------------------------------------------------------------------------
// K1: 128x128-tile fused GEMM -> partial scores.  2048 blocks (bm 512 x bn 4),
// 256 threads (4 waves, 2x2), BK=64, single-buffered LDS (m97 structure,
// 3 blocks/CU for cross-block latency hiding).
// spart[bn][m] = sum_{col in bn-slice} tanh(h[m][col]+b1[col]) * W2[col]
// ---------------------------------------------------------------------------
__global__ __launch_bounds__(256, 3) void k_gemm_score(
    const float* __restrict__ leaves, const float* __restrict__ anc,
    const bf16* __restrict__ W1t, const float* __restrict__ b1,
    const float* __restrict__ W2, float* __restrict__ spart) {
  __shared__ bf16 ldsA[BM * BK];  // 16 KiB
  __shared__ bf16 ldsB[BN * BK];  // 16 KiB

  const int t    = threadIdx.x;
  const int lane = t & 63;
  const int wave = t >> 6;
  const int l15  = lane & 15;
  const int l4   = lane >> 4;
  const int wm2  = wave >> 1;  // 0..1
  const int wn2  = wave & 1;   // 0..1
  const int bn   = blockIdx.x & 3;
  const int bm   = blockIdx.x >> 2;
  const int m0   = bm * BM;
  const int n0   = bn * BN;

  // A staging: 2 threads/row, 32 f32 (4 chunks of 8) each
  const int ar   = t >> 1;       // 0..127
  const int half = t & 1;        // chunk base = half*4

  const f32x4 zero4 = {0.f, 0.f, 0.f, 0.f};
  f32x4 acc[4][4];
  #pragma unroll
  for (int i = 0; i < 4; ++i)
    #pragma unroll
    for (int j = 0; j < 4; ++j) acc[i][j] = zero4;

  for (int kb = 0; kb < NKB; ++kb) {
    // ---- B: 16 KiB image -> LDS via DMA (4 issues/wave), linear dest ----
    const bf16* Bsrc = W1t + (size_t)(kb * 4 + bn) * (BN * BK);
    #pragma unroll
    for (int j = 0; j < 4; ++j)
      gload_lds16(Bsrc + ((size_t)(wave * 4 + j) * 64 + lane) * 8,
                  ldsB + (wave * 4 + j) * 512);
    // ---- A: f32 -> regs -> bf16 -> swizzled LDS ----
    const float* Ap = ((kb < 16)
        ? leaves + (size_t)(m0 + ar) * EMB + (size_t)kb * BK
        : anc    + (size_t)(m0 + ar) * EMB + (size_t)(kb - 16) * BK)
        + half * 32;
    float4 v0 = *(const float4*)(Ap + 0);
    float4 v1 = *(const float4*)(Ap + 4);
    float4 v2 = *(const float4*)(Ap + 8);
    float4 v3 = *(const float4*)(Ap + 12);
    float4 v4 = *(const float4*)(Ap + 16);
    float4 v5 = *(const float4*)(Ap + 20);
    float4 v6 = *(const float4*)(Ap + 24);
    float4 v7 = *(const float4*)(Ap + 28);
    {
      bf16x8 o0 = {(bf16)v0.x, (bf16)v0.y, (bf16)v0.z, (bf16)v0.w,
                   (bf16)v1.x, (bf16)v1.y, (bf16)v1.z, (bf16)v1.w};
      bf16x8 o1 = {(bf16)v2.x, (bf16)v2.y, (bf16)v2.z, (bf16)v2.w,
                   (bf16)v3.x, (bf16)v3.y, (bf16)v3.z, (bf16)v3.w};
      bf16x8 o2 = {(bf16)v4.x, (bf16)v4.y, (bf16)v4.z, (bf16)v4.w,
                   (bf16)v5.x, (bf16)v5.y, (bf16)v5.z, (bf16)v5.w};
      bf16x8 o3 = {(bf16)v6.x, (bf16)v6.y, (bf16)v6.z, (bf16)v6.w,
                   (bf16)v7.x, (bf16)v7.y, (bf16)v7.z, (bf16)v7.w};
      const int c0 = half * 4;
      *(bf16x8*)(ldsA + ar * BK + ((c0 + 0) ^ (ar & 7)) * 8) = o0;
      *(bf16x8*)(ldsA + ar * BK + ((c0 + 1) ^ (ar & 7)) * 8) = o1;
      *(bf16x8*)(ldsA + ar * BK + ((c0 + 2) ^ (ar & 7)) * 8) = o2;
      *(bf16x8*)(ldsA + ar * BK + ((c0 + 3) ^ (ar & 7)) * 8) = o3;
    }
    __syncthreads();
    // ---- compute ----
    #pragma unroll
    for (int ks = 0; ks < 2; ++ks) {
      bf16x8 af[4], bfr[4];
      #pragma unroll
      for (int mi = 0; mi < 4; ++mi) {
        const int row = wm2 * 64 + mi * 16 + l15;
        const int p   = (ks * 4 + l4) ^ (row & 7);
        af[mi] = *(const bf16x8*)(ldsA + row * BK + p * 8);
      }
      #pragma unroll
      for (int ni = 0; ni < 4; ++ni) {
        const int nrow = wn2 * 64 + ni * 16 + l15;
        const int p    = (ks * 4 + l4) ^ (nrow & 7);
        bfr[ni] = *(const bf16x8*)(ldsB + nrow * BK + p * 8);
      }
      #pragma unroll
      for (int ni = 0; ni < 4; ++ni)
        #pragma unroll
        for (int mi = 0; mi < 4; ++mi)
          acc[mi][ni] = __builtin_amdgcn_mfma_f32_16x16x32_bf16(
              af[mi], bfr[ni], acc[mi][ni], 0, 0, 0);
    }
    __syncthreads();
  }

  // ---- epilogue: partial score over this block's 128 cols ----
  // acc[mi][ni][r]: row = wm2*64+mi*16+l4*4+r, col = wn2*64+ni*16+l15
  float b1c[4], w2c[4];
  #pragma unroll
  for (int ni = 0; ni < 4; ++ni) {
    const int col = n0 + wn2 * 64 + ni * 16 + l15;
    b1c[ni] = b1[col];
    w2c[ni] = W2[col];
  }
  float* sp = (float*)ldsA;  // 256 floats
  #pragma unroll
  for (int mi = 0; mi < 4; ++mi) {
    #pragma unroll
    for (int r = 0; r < 4; ++r) {
      float p = 0.f;
      #pragma unroll
      for (int ni = 0; ni < 4; ++ni)
        p += tanhf(acc[mi][ni][r] + b1c[ni]) * w2c[ni];
      p += __shfl_xor(p, 1);
      p += __shfl_xor(p, 2);
      p += __shfl_xor(p, 4);
      p += __shfl_xor(p, 8);
      if (l15 == 0) sp[wn2 * 128 + wm2 * 64 + mi * 16 + l4 * 4 + r] = p;
    }
  }
  __syncthreads();
  if (t < BM)
    spart[(size_t)bn * N_ROWS + m0 + t] = sp[t] + sp[128 + t];
}

// ---------------------------------------------------------------------------
// K2: combine 4 partials -> scores; per-128-row block max & sumexp.
// ---------------------------------------------------------------------------
__global__ __launch_bounds__(128) void k_combine(
    const float* __restrict__ spart, const float* __restrict__ b2,
    float* __restrict__ scores, float* __restrict__ bmax,
    float* __restrict__ bsum) {
  const int b = blockIdx.x, t = threadIdx.x;
  const int lane = t & 63, wave = t >> 6;
  const int m = b * 128 + t;
  __shared__ float rm[2], rs[2];
  const float s = spart[m] + spart[N_ROWS + m] + spart[2 * N_ROWS + m] +
                  spart[3 * N_ROWS + m] + b2[0];
  scores[m] = s;
  float mm = s;
  #pragma unroll
  for (int o = 32; o; o >>= 1) mm = fmaxf(mm, __shfl_xor(mm, o));
  if (lane == 0) rm[wave] = mm;
  __syncthreads();
  const float bM = fmaxf(rm[0], rm[1]);
  float ee = __expf(s - bM);
  #pragma unroll
  for (int o = 32; o; o >>= 1) ee += __shfl_xor(ee, o);
  if (lane == 0) rs[wave] = ee;
  __syncthreads();
  if (t == 0) {
    bmax[b] = bM;
    bsum[b] = rs[0] + rs[1];
  }
}

// ---------------------------------------------------------------------------
// K3: global M, Z and per-block rescale factors scale[b] = exp(bmax[b]-M).
// ---------------------------------------------------------------------------
__global__ __launch_bounds__(512) void k_mz(const float* __restrict__ bmax,
                                            const float* __restrict__ bsum,
                                            float* __restrict__ MZ,
                                            float* __restrict__ scale) {
  const int t = threadIdx.x, lane = t & 63, wave = t >> 6;
  __shared__ float rm[8], rs[8];
  const float m = bmax[t];
  float mm = m;
  #pragma unroll
  for (int o = 32; o; o >>= 1) mm = fmaxf(mm, __shfl_xor(mm, o));
  if (lane == 0) rm[wave] = mm;
  __syncthreads();
  if (t == 0) {
    float g = rm[0];
    for (int i = 1; i < 8; ++i) g = fmaxf(g, rm[i]);
    rm[0] = g;
  }
  __syncthreads();
  const float M = rm[0];
  const float sc = __expf(m - M);
  scale[t] = sc;
  float z = bsum[t] * sc;
  #pragma unroll
  for (int o = 32; o; o >>= 1) z += __shfl_xor(z, o);
  if (lane == 0) rs[wave] = z;
  __syncthreads();
  if (t == 0) {
    float Z = 0.f;
    for (int i = 0; i < 8; ++i) Z += rs[i];
    MZ[0] = M;
    MZ[1] = Z;
  }
}

// ---------------------------------------------------------------------------
// K4: part[b][j] = sum_i exp(s_i - bmax[b]) * anc[b*128+i][j]   (local max!)
// ---------------------------------------------------------------------------
__global__ __launch_bounds__(256) void k_part(const float* __restrict__ anc,
                                              const float* __restrict__ scores,
                                              const float* __restrict__ bmax,
                                              float* __restrict__ part) {
  __shared__ float w[BM];
  const int b = blockIdx.x, t = threadIdx.x;
  const float bM = bmax[b];
  if (t < BM) w[t] = __expf(scores[(size_t)b * BM + t] - bM);
  __syncthreads();
  float4 a = {0.f, 0.f, 0.f, 0.f};
  const float4* src = (const float4*)(anc + (size_t)b * BM * EMB) + t;
  #pragma unroll 4
  for (int i = 0; i < BM; ++i) {
    float4 v = src[i * (EMB / 4)];
    const float wi = w[i];
    a.x += wi * v.x;
    a.y += wi * v.y;
    a.z += wi * v.z;
    a.w += wi * v.w;
  }
  ((float4*)(part + (size_t)b * EMB))[t] = a;
}

// ---------------------------------------------------------------------------
// K5: out[j] = (sum_b part[b][j] * scale[b]) / Z
// ---------------------------------------------------------------------------
__global__ __launch_bounds__(256) void k_final(const float* __restrict__ part,
                                               const float* __restrict__ scale,
                                               const float* __restrict__ MZ,
                                               float* __restrict__ out) {
  const int j = blockIdx.x * 256 + threadIdx.x;
  float s0 = 0.f, s1 = 0.f, s2 = 0.f, s3 = 0.f;
  for (int b = 0; b < MBLK; b += 4) {
    s0 += part[(size_t)(b + 0) * EMB + j] * scale[b + 0];
    s1 += part[(size_t)(b + 1) * EMB + j] * scale[b + 1];
    s2 += part[(size_t)(b + 2) * EMB + j] * scale[b + 2];
    s3 += part[(size_t)(b + 3) * EMB + j] * scale[b + 3];
  }
  out[j] = (s0 + s1 + s2 + s3) / MZ[1];
}

extern "C" void kernel_launch(void* const* d_in, const int* in_sizes, int n_in,
                              void* d_out, int out_size, void* d_ws,
                              size_t ws_size, hipStream_t stream) {
  const float* leaves = (const float*)d_in[0];
  const float* anc    = (const float*)d_in[1];
  const float* W1     = (const float*)d_in[2];
  const float* b1     = (const float*)d_in[3];
  const float* W2     = (const float*)d_in[4];
  const float* b2     = (const float*)d_in[5];
  float* out = (float*)d_out;

  char* ws = (char*)d_ws;
  bf16*  W1t    = (bf16*)ws;                                   // 2 MiB
  float* spart  = (float*)(ws + (2u << 20));                   // 1 MiB
  float* scores = (float*)(ws + (3u << 20));                   // 256 KiB
  float* bmax   = (float*)(ws + (3u << 20) + (1u << 18));      // 2 KiB
  float* bsum   = bmax + MBLK;                                 // 2 KiB
  float* scale  = bsum + MBLK;                                 // 2 KiB
  float* MZ     = scale + MBLK;                                // 8 B
  float* part   = (float*)(ws + (4u << 20));                   // 2 MiB

  k_prep_w1<<<dim3(32, 4), 256, 0, stream>>>(W1, W1t);
  k_gemm_score<<<dim3(MBLK * NSPL), 256, 0, stream>>>(leaves, anc, W1t, b1, W2,
                                                      spart);
  k_combine<<<dim3(MBLK), 128, 0, stream>>>(spart, b2, scores, bmax, bsum);
  k_mz<<<dim3(1), 512, 0, stream>>>(bmax, bsum, MZ, scale);
  k_part<<<dim3(MBLK), 256, 0, stream>>>(anc, scores, bmax, part);
  k_final<<<dim3(EMB / 256), 256, 0, stream>>>(part, scale, MZ, out);
}

// Round 5
// 290.368 us; speedup vs baseline: 1.7418x; 1.4130x over previous
//
#include <hip/hip_runtime.h>
#include <hip/hip_bf16.h>
#include <stdint.h>
#include <stddef.h>

typedef __bf16 bf16;
typedef bf16 bf16x8 __attribute__((ext_vector_type(8)));
typedef float f32x4 __attribute__((ext_vector_type(4)));

#define N_ROWS 65536
#define EMB    1024
#define ATTD   512
#define KDIM   2048
#define BM     128
#define BN     128
#define BK     64
#define NKB    (KDIM / BK)     // 32 K-tiles
#define MBLK   (N_ROWS / BM)   // 512 row-blocks
#define NSPL   (ATTD / BN)     // 4 col-blocks

__device__ __forceinline__ void gload_lds16(const void* g, void* l) {
  __builtin_amdgcn_global_load_lds(
      (const __attribute__((address_space(1))) void*)g,
      (__attribute__((address_space(3))) void*)l, 16, 0, 0);
}

// ---------------------------------------------------------------------------
// K0: W1 [2048x512] f32 -> W1t bf16: 32x4 per-(kb,bn) 16 KiB images.
// Image (kb,bn), elem (n*8+p)*8+e  holds  W1[kb*64 + (p^(n&7))*8 + e][bn*128+n].
// ---------------------------------------------------------------------------
__global__ __launch_bounds__(256) void k_prep_w1(const float* __restrict__ W1,
                                                 bf16* __restrict__ W1t) {
  __shared__ float tile[64][132];
  const int kb = blockIdx.x;   // 0..31
  const int bn = blockIdx.y;   // 0..3
  const int t  = threadIdx.x;  // 0..255

  const int kr = t >> 2;             // 0..63
  const int nc = (t & 3) * 32;       // 0,32,64,96
  const float* src = W1 + (size_t)(kb * 64 + kr) * ATTD + bn * 128 + nc;
  #pragma unroll
  for (int q = 0; q < 8; ++q) {
    float4 v = *(const float4*)(src + q * 4);
    tile[kr][nc + q * 4 + 0] = v.x;
    tile[kr][nc + q * 4 + 1] = v.y;
    tile[kr][nc + q * 4 + 2] = v.z;
    tile[kr][nc + q * 4 + 3] = v.w;
  }
  __syncthreads();

  const int nl = t >> 1;             // 0..127
  const int pb = (t & 1) * 4;
  bf16* dst = W1t + (size_t)(kb * 4 + bn) * (BN * BK);
  #pragma unroll
  for (int pi = 0; pi < 4; ++pi) {
    const int p = pb + pi;
    const int c = p ^ (nl & 7);
    bf16x8 o;
    #pragma unroll
    for (int e = 0; e < 8; ++e) o[e] = (bf16)tile[c * 8 + e][nl];
    *(bf16x8*)(dst + ((size_t)nl * 8 + p) * 8) = o;
  }
}

// ---------------------------------------------------------------------------
// K1: 128x128-tile fused GEMM -> partial scores.  2048 blocks, 256 thr
// (4 waves 2x2), BK=64, single-buffered LDS, 3 blocks/CU.
// Changes vs R4:
//  * XCD-affinity remap: the 4 bn-sharers of one row-slab sit 8 apart in
//    dispatch id -> same XCD -> per-kb A-tile L2 reuse (cuts HBM A-refetch).
//  * A staged via global_load_lds as f32 with pre-swizzled SOURCE address
//    (linear LDS dest, rule #21); f32->bf16 conversion at fragment read.
//    Zero staging VGPRs; 12 fire-and-forget DMA issues/thread/iter.
// spart[bn][m] = sum_{col in bn-slice} tanh(h[m][col]+b1[col]) * W2[col]
// ---------------------------------------------------------------------------
__global__ __launch_bounds__(256, 3) void k_gemm_score(
    const float* __restrict__ leaves, const float* __restrict__ anc,
    const bf16* __restrict__ W1t, const float* __restrict__ b1,
    const float* __restrict__ W2, float* __restrict__ spart) {
  __shared__ float ldsAf[BM * BK];  // 32 KiB f32, pair-swizzled
  __shared__ bf16  ldsB[BN * BK];   // 16 KiB bf16, chunk-swizzled

  const int t    = threadIdx.x;
  const int lane = t & 63;
  const int wave = t >> 6;
  const int l15  = lane & 15;
  const int l4   = lane >> 4;
  const int wm2  = wave >> 1;  // 0..1
  const int wn2  = wave & 1;   // 0..1

  // --- XCD-affinity remap: g -> (bm, bn) s.t. the 4 bn-sharers of each bm
  //     have dispatch ids {base, base+8, base+16, base+24} (same XCD). ---
  const int g   = blockIdx.x;
  const int sb  = g >> 5;        // superblock 0..63
  const int q   = g & 31;
  const int bn  = q >> 3;        // 0..3
  const int bm  = sb * 8 + (q & 7);
  const int m0  = bm * BM;
  const int n0  = bn * BN;

  // --- A DMA source pre-swizzle (per-thread constants) ---
  // chunk L = s*256 + t; r = s*16 + (t>>4); phys pair (t>>1)&7, half t&1;
  // logical pair = ppair ^ (r&7), r&7 == (t>>4)&7.
  const int a_rbase = t >> 4;                        // row for s=0; +16 per s
  const int a_lpair = ((t >> 1) & 7) ^ ((t >> 4) & 7);
  const int a_koff  = a_lpair * 8 + (t & 1) * 4;     // f32 offset in k-window

  const f32x4 zero4 = {0.f, 0.f, 0.f, 0.f};
  f32x4 acc[4][4];
  #pragma unroll
  for (int i = 0; i < 4; ++i)
    #pragma unroll
    for (int j = 0; j < 4; ++j) acc[i][j] = zero4;

  for (int kb = 0; kb < NKB; ++kb) {
    // ---- B: 16 KiB pre-swizzled image -> LDS (linear dest) ----
    const bf16* Bsrc = W1t + (size_t)(kb * 4 + bn) * (BN * BK);
    #pragma unroll
    for (int j = 0; j < 4; ++j)
      gload_lds16(Bsrc + ((size_t)(wave * 4 + j) * 64 + lane) * 8,
                  ldsB + (wave * 4 + j) * 512);
    // ---- A: f32 DMA, pre-swizzled source, linear dest ----
    const float* Abase = (kb < 16)
        ? leaves + (size_t)m0 * EMB + (size_t)kb * BK
        : anc    + (size_t)m0 * EMB + (size_t)(kb - 16) * BK;
    #pragma unroll
    for (int s = 0; s < 8; ++s) {
      const int r = s * 16 + a_rbase;
      gload_lds16(Abase + (size_t)r * EMB + a_koff,
                  ldsAf + (s * 256 + t) * 4);
    }
    __syncthreads();
    // ---- compute ----
    #pragma unroll
    for (int ks = 0; ks < 2; ++ks) {
      bf16x8 af[4], bfr[4];
      #pragma unroll
      for (int mi = 0; mi < 4; ++mi) {
        const int row   = wm2 * 64 + mi * 16 + l15;
        const int ppair = (ks * 4 + l4) ^ (row & 7);
        const float* ap = ldsAf + row * BK + ppair * 8;
        f32x4 lo = *(const f32x4*)(ap);
        f32x4 hi = *(const f32x4*)(ap + 4);
        af[mi] = (bf16x8){(bf16)lo.x, (bf16)lo.y, (bf16)lo.z, (bf16)lo.w,
                          (bf16)hi.x, (bf16)hi.y, (bf16)hi.z, (bf16)hi.w};
      }
      #pragma unroll
      for (int ni = 0; ni < 4; ++ni) {
        const int nrow = wn2 * 64 + ni * 16 + l15;
        const int p    = (ks * 4 + l4) ^ (nrow & 7);
        bfr[ni] = *(const bf16x8*)(ldsB + nrow * BK + p * 8);
      }
      #pragma unroll
      for (int ni = 0; ni < 4; ++ni)
        #pragma unroll
        for (int mi = 0; mi < 4; ++mi)
          acc[mi][ni] = __builtin_amdgcn_mfma_f32_16x16x32_bf16(
              af[mi], bfr[ni], acc[mi][ni], 0, 0, 0);
    }
    __syncthreads();
  }

  // ---- epilogue: partial score over this block's 128 cols ----
  // acc[mi][ni][r]: row = wm2*64+mi*16+l4*4+r, col = wn2*64+ni*16+l15
  float b1c[4], w2c[4];
  #pragma unroll
  for (int ni = 0; ni < 4; ++ni) {
    const int col = n0 + wn2 * 64 + ni * 16 + l15;
    b1c[ni] = b1[col];
    w2c[ni] = W2[col];
  }
  float* sp = ldsAf;  // 256 floats scratch
  #pragma unroll
  for (int mi = 0; mi < 4; ++mi) {
    #pragma unroll
    for (int r = 0; r < 4; ++r) {
      float p = 0.f;
      #pragma unroll
      for (int ni = 0; ni < 4; ++ni)
        p += tanhf(acc[mi][ni][r] + b1c[ni]) * w2c[ni];
      p += __shfl_xor(p, 1);
      p += __shfl_xor(p, 2);
      p += __shfl_xor(p, 4);
      p += __shfl_xor(p, 8);
      if (l15 == 0) sp[wn2 * 128 + wm2 * 64 + mi * 16 + l4 * 4 + r] = p;
    }
  }
  __syncthreads();
  if (t < BM)
    spart[(size_t)bn * N_ROWS + m0 + t] = sp[t] + sp[128 + t];
}

// ---------------------------------------------------------------------------
// K2: combine 4 partials -> scores; per-128-row block max & sumexp.
// ---------------------------------------------------------------------------
__global__ __launch_bounds__(128) void k_combine(
    const float* __restrict__ spart, const float* __restrict__ b2,
    float* __restrict__ scores, float* __restrict__ bmax,
    float* __restrict__ bsum) {
  const int b = blockIdx.x, t = threadIdx.x;
  const int lane = t & 63, wave = t >> 6;
  const int m = b * 128 + t;
  __shared__ float rm[2], rs[2];
  const float s = spart[m] + spart[N_ROWS + m] + spart[2 * N_ROWS + m] +
                  spart[3 * N_ROWS + m] + b2[0];
  scores[m] = s;
  float mm = s;
  #pragma unroll
  for (int o = 32; o; o >>= 1) mm = fmaxf(mm, __shfl_xor(mm, o));
  if (lane == 0) rm[wave] = mm;
  __syncthreads();
  const float bM = fmaxf(rm[0], rm[1]);
  float ee = __expf(s - bM);
  #pragma unroll
  for (int o = 32; o; o >>= 1) ee += __shfl_xor(ee, o);
  if (lane == 0) rs[wave] = ee;
  __syncthreads();
  if (t == 0) {
    bmax[b] = bM;
    bsum[b] = rs[0] + rs[1];
  }
}

// ---------------------------------------------------------------------------
// K3: global M, Z and per-block rescale factors scale[b] = exp(bmax[b]-M).
// ---------------------------------------------------------------------------
__global__ __launch_bounds__(512) void k_mz(const float* __restrict__ bmax,
                                            const float* __restrict__ bsum,
                                            float* __restrict__ MZ,
                                            float* __restrict__ scale) {
  const int t = threadIdx.x, lane = t & 63, wave = t >> 6;
  __shared__ float rm[8], rs[8];
  const float m = bmax[t];
  float mm = m;
  #pragma unroll
  for (int o = 32; o; o >>= 1) mm = fmaxf(mm, __shfl_xor(mm, o));
  if (lane == 0) rm[wave] = mm;
  __syncthreads();
  if (t == 0) {
    float g = rm[0];
    for (int i = 1; i < 8; ++i) g = fmaxf(g, rm[i]);
    rm[0] = g;
  }
  __syncthreads();
  const float M = rm[0];
  const float sc = __expf(m - M);
  scale[t] = sc;
  float z = bsum[t] * sc;
  #pragma unroll
  for (int o = 32; o; o >>= 1) z += __shfl_xor(z, o);
  if (lane == 0) rs[wave] = z;
  __syncthreads();
  if (t == 0) {
    float Z = 0.f;
    for (int i = 0; i < 8; ++i) Z += rs[i];
    MZ[0] = M;
    MZ[1] = Z;
  }
}

// ---------------------------------------------------------------------------
// K4: part[b][j] = sum_i exp(s_i - bmax[b]) * anc[b*128+i][j]   (local max)
// ---------------------------------------------------------------------------
__global__ __launch_bounds__(256) void k_part(const float* __restrict__ anc,
                                              const float* __restrict__ scores,
                                              const float* __restrict__ bmax,
                                              float* __restrict__ part) {
  __shared__ float w[BM];
  const int b = blockIdx.x, t = threadIdx.x;
  const float bM = bmax[b];
  if (t < BM) w[t] = __expf(scores[(size_t)b * BM + t] - bM);
  __syncthreads();
  float4 a = {0.f, 0.f, 0.f, 0.f};
  const float4* src = (const float4*)(anc + (size_t)b * BM * EMB) + t;
  #pragma unroll 4
  for (int i = 0; i < BM; ++i) {
    float4 v = src[i * (EMB / 4)];
    const float wi = w[i];
    a.x += wi * v.x;
    a.y += wi * v.y;
    a.z += wi * v.z;
    a.w += wi * v.w;
  }
  ((float4*)(part + (size_t)b * EMB))[t] = a;
}

// ---------------------------------------------------------------------------
// K5: out[j] = (sum_b part[b][j] * scale[b]) / Z
// ---------------------------------------------------------------------------
__global__ __launch_bounds__(256) void k_final(const float* __restrict__ part,
                                               const float* __restrict__ scale,
                                               const float* __restrict__ MZ,
                                               float* __restrict__ out) {
  const int j = blockIdx.x * 256 + threadIdx.x;
  float s0 = 0.f, s1 = 0.f, s2 = 0.f, s3 = 0.f;
  for (int b = 0; b < MBLK; b += 4) {
    s0 += part[(size_t)(b + 0) * EMB + j] * scale[b + 0];
    s1 += part[(size_t)(b + 1) * EMB + j] * scale[b + 1];
    s2 += part[(size_t)(b + 2) * EMB + j] * scale[b + 2];
    s3 += part[(size_t)(b + 3) * EMB + j] * scale[b + 3];
  }
  out[j] = (s0 + s1 + s2 + s3) / MZ[1];
}

extern "C" void kernel_launch(void* const* d_in, const int* in_sizes, int n_in,
                              void* d_out, int out_size, void* d_ws,
                              size_t ws_size, hipStream_t stream) {
  const float* leaves = (const float*)d_in[0];
  const float* anc    = (const float*)d_in[1];
  const float* W1     = (const float*)d_in[2];
  const float* b1     = (const float*)d_in[3];
  const float* W2     = (const float*)d_in[4];
  const float* b2     = (const float*)d_in[5];
  float* out = (float*)d_out;

  char* ws = (char*)d_ws;
  bf16*  W1t    = (bf16*)ws;                                   // 2 MiB
  float* spart  = (float*)(ws + (2u << 20));                   // 1 MiB
  float* scores = (float*)(ws + (3u << 20));                   // 256 KiB
  float* bmax   = (float*)(ws + (3u << 20) + (1u << 18));      // 2 KiB
  float* bsum   = bmax + MBLK;                                 // 2 KiB
  float* scale  = bsum + MBLK;                                 // 2 KiB
  float* MZ     = scale + MBLK;                                // 8 B
  float* part   = (float*)(ws + (4u << 20));                   // 2 MiB

  k_prep_w1<<<dim3(32, 4), 256, 0, stream>>>(W1, W1t);
  k_gemm_score<<<dim3(MBLK * NSPL), 256, 0, stream>>>(leaves, anc, W1t, b1, W2,
                                                      spart);
  k_combine<<<dim3(MBLK), 128, 0, stream>>>(spart, b2, scores, bmax, bsum);
  k_mz<<<dim3(1), 512, 0, stream>>>(bmax, bsum, MZ, scale);
  k_part<<<dim3(MBLK), 256, 0, stream>>>(anc, scores, bmax, part);
  k_final<<<dim3(EMB / 256), 256, 0, stream>>>(part, scale, MZ, out);
}